// Round 4
// baseline (10848.451 us; speedup 1.0000x reference)
//
#include <hip/hip_runtime.h>
#include <hip/hip_bf16.h>

typedef __attribute__((ext_vector_type(8))) short short8;
typedef __attribute__((ext_vector_type(4))) float f32x4;

#define T_STEPS 512
#define BATCH 64
#define HID 1024
#define DIN 512
#define NBLOCKS 128
#define NTHREADS 512

// ---- workspace layout (bytes) ----
#define WS_SLOTS 0              // 128 * 4B barrier slots (slot[b] = last interval block b signaled)
#define WS_H0 4096              // 2 * 131072 (double-buffered h0, bf16 frag tiles)
#define WS_H1 (4096 + 262144)   // 2 * 131072
#define WS_XB (1u << 20)        // x cast to bf16 frag tiles: 512*4*16*1024 = 32 MB
#define HBUF 131072

#define MFMA __builtin_amdgcn_mfma_f32_16x16x32_bf16

__device__ __forceinline__ short bf16r(float x) {
  unsigned u = __builtin_bit_cast(unsigned, x);
  u += 0x7FFFu + ((u >> 16) & 1u);   // round-to-nearest-even
  return (short)(u >> 16);
}

__device__ __forceinline__ float sigf(float x) {
  return 1.0f / (1.0f + __expf(-x));
}
__device__ __forceinline__ float tanh_(float x) {
  return 2.0f * sigf(2.0f * x) - 1.0f;
}

__device__ __forceinline__ short8 pack8(const float* p) {
  float4 a = *(const float4*)p;
  float4 c = *(const float4*)(p + 4);
  short8 v;
  v[0] = bf16r(a.x); v[1] = bf16r(a.y); v[2] = bf16r(a.z); v[3] = bf16r(a.w);
  v[4] = bf16r(c.x); v[5] = bf16r(c.y); v[6] = bf16r(c.z); v[7] = bf16r(c.w);
  return v;
}

// Wave-level barrier wait: spin until every block's slot >= tgt, then acquire.
// Each of the 64 lanes watches 2 slots; exit is wave-collective (__any).
// Guard: legitimate waits are ~µs; 2^17 iterations ≈ several ms. If logic is
// ever wrong this produces a fast wrong answer, never a watchdog hang.
__device__ __forceinline__ void wave_wait(const unsigned* slots, unsigned tgt, int lane) {
  unsigned a, b;
  int guard = 0;
  do {
    a = __hip_atomic_load(&slots[lane], __ATOMIC_RELAXED, __HIP_MEMORY_SCOPE_AGENT);
    b = __hip_atomic_load(&slots[lane + 64], __ATOMIC_RELAXED, __HIP_MEMORY_SCOPE_AGENT);
    if (++guard > (1 << 17)) break;   // anti-hang bail (corrupts, never deadlocks)
  } while (__any(a < tgt || b < tgt));
  // acquire: invalidate L1/L2 so cached h reads see peers' released data
  __builtin_amdgcn_fence(__ATOMIC_ACQUIRE, "agent");
}

// Cast x [64][512][512] fp32 -> bf16 MFMA A-fragment tiles:
// xb[t][m=b/16][kt=k/32] tile of 1024B; within tile: lane=(b&15)+16*((k>>3)&3), elem=k&7
__global__ void cast_x_kernel(const float* __restrict__ x, unsigned char* __restrict__ ws) {
  unsigned char* xb = ws + WS_XB;
  int idx = blockIdx.x * blockDim.x + threadIdx.x;   // 0..262143
  for (int c = idx; c < 64 * 512 * 64; c += 262144) {
    const int b = c >> 15;          // /(512*64)
    const int t = (c >> 6) & 511;
    const int kc = c & 63;          // 8-elem chunk index along K=512
    const float* src = x + (((b << 9) + t) << 9) + (kc << 3);
    short8 v = pack8(src);
    const int kt = kc >> 2;
    const int ln = (b & 15) + ((kc & 3) << 4);
    unsigned char* dst = xb + (((t << 2) + (b >> 4)) * 16 + kt) * 1024 + ln * 16;
    *(short8*)dst = v;
  }
}

__global__ __launch_bounds__(NTHREADS, 2) void lstm_main(
    const float* __restrict__ Wih0, const float* __restrict__ Whh0,
    const float* __restrict__ bih0, const float* __restrict__ bhh0,
    const float* __restrict__ Wih1, const float* __restrict__ Whh1,
    const float* __restrict__ bih1, const float* __restrict__ bhh1,
    float* __restrict__ out, unsigned char* __restrict__ ws)
{
  __shared__ float red[8][4][2][64][4];   // [wave][Mtile][Ntile][lane][reg] = 64 KB

  const int tid = threadIdx.x;
  const int wid = tid >> 6;
  const int lane = tid & 63;
  const int blk = blockIdx.x;

  unsigned* slots = (unsigned*)(ws + WS_SLOTS);
  unsigned char* h0b = ws + WS_H0;
  unsigned char* h1b = ws + WS_H1;
  const unsigned char* xb = ws + WS_XB;

  // ---------- persistent weight fragments (128 VGPRs) ----------
  // Block owns gate columns col = blk*8 + (0..7) for BOTH layers.
  // Ntile n in 0..31: gate = n>>3 (i,f,g,o), col = blk*8 + (n&7); weight row = gate*1024+col.
  // B-fragment slot (lane, e): n = lane&15 (+16*nt), k = kbase + 8*(lane>>4) + e.
  short8 wf[32];
  {
    const int hi8 = (lane >> 4) << 3;
    if (wid < 4) {
      // A-waves: layer0. x-ktiles wid*4+i (i<4), h0-ktiles wid*8+i (i<8)
#pragma unroll
      for (int nt = 0; nt < 2; ++nt) {
        const int n = nt * 16 + (lane & 15);
        const int row = ((n >> 3) << 10) + blk * 8 + (n & 7);
#pragma unroll
        for (int i = 0; i < 4; ++i) {
          const int k = (wid * 4 + i) * 32 + hi8;
          wf[i * 2 + nt] = pack8(Wih0 + row * DIN + k);
        }
#pragma unroll
        for (int i = 0; i < 8; ++i) {
          const int k = (wid * 8 + i) * 32 + hi8;
          wf[8 + i * 2 + nt] = pack8(Whh0 + row * HID + k);
        }
      }
    } else {
      // B-waves: layer1. h0-ktiles w2*8+i and h1-ktiles w2*8+i
      const int w2 = wid - 4;
#pragma unroll
      for (int nt = 0; nt < 2; ++nt) {
        const int n = nt * 16 + (lane & 15);
        const int row = ((n >> 3) << 10) + blk * 8 + (n & 7);
#pragma unroll
        for (int i = 0; i < 8; ++i) {
          const int k = (w2 * 8 + i) * 32 + hi8;
          wf[i * 2 + nt] = pack8(Wih1 + row * HID + k);
          wf[16 + i * 2 + nt] = pack8(Whh1 + row * HID + k);
        }
      }
    }
  }

  // ---------- per-thread epilogue state ----------
  const int j = tid & 7;
  const int b = tid >> 3;          // batch row 0..63
  const int jg = blk * 8 + j;      // global h column
  const int m = b >> 4;            // Mtile
  const int r = b & 15;            // row within tile
  float bias0[4], bias1[4];
#pragma unroll
  for (int g = 0; g < 4; ++g) {
    bias0[g] = bih0[g * HID + jg] + bhh0[g * HID + jg];
    bias1[g] = bih1[g * HID + jg] + bhh1[g * HID + jg];
  }
  float c0 = 0.0f, c1 = 0.0f;
  // byte offset of h(b, jg) inside one parity buffer (frag tile layout)
  const int hoff = ((b >> 4) * 32 + (jg >> 5)) * 1024 +
                   ((b & 15) + 16 * ((jg >> 3) & 3)) * 16 + (jg & 7) * 2;

  // ---------- wavefront loop: interval s computes layer0(s) and layer1(s-1) ----------
  for (int s = 0; s <= T_STEPS; ++s) {
    const int p0 = s & 1;
    const unsigned char* h0r = h0b + (p0 ^ 1) * HBUF;   // h0(s-1)

    if (wid < 4) {
      if (s < T_STEPS) {
        const unsigned char* xs = xb + s * 65536;
        f32x4 acc[4][2];
        // x part first — no barrier dependency, overlaps the wait below
#pragma unroll
        for (int mm = 0; mm < 4; ++mm) {
          acc[mm][0] = (f32x4){0.f, 0.f, 0.f, 0.f};
          acc[mm][1] = (f32x4){0.f, 0.f, 0.f, 0.f};
#pragma unroll
          for (int i = 0; i < 4; ++i) {
            short8 af = *(const short8*)(xs + (mm * 16 + wid * 4 + i) * 1024 + lane * 16);
            acc[mm][0] = MFMA(af, wf[i * 2 + 0], acc[mm][0], 0, 0, 0);
            acc[mm][1] = MFMA(af, wf[i * 2 + 1], acc[mm][1], 0, 0, 0);
          }
        }
        wave_wait(slots, (unsigned)s, lane);   // h0(s-1) ready device-wide
#pragma unroll
        for (int mm = 0; mm < 4; ++mm) {
#pragma unroll
          for (int i = 0; i < 8; ++i) {
            short8 af = *(const short8*)(h0r + (mm * 32 + wid * 8 + i) * 1024 + lane * 16);
            acc[mm][0] = MFMA(af, wf[8 + i * 2 + 0], acc[mm][0], 0, 0, 0);
            acc[mm][1] = MFMA(af, wf[8 + i * 2 + 1], acc[mm][1], 0, 0, 0);
          }
          *(f32x4*)(&red[wid][mm][0][lane][0]) = acc[mm][0];
          *(f32x4*)(&red[wid][mm][1][lane][0]) = acc[mm][1];
        }
      }
    } else {
      if (s >= 1) {
        wave_wait(slots, (unsigned)s, lane);   // h0(s-1), h1(s-2) ready
        const unsigned char* h1r = h1b + p0 * HBUF;     // h1(s-2)
        const int w2 = wid - 4;
        for (int mm = 0; mm < 4; ++mm) {
          f32x4 a0 = {0.f, 0.f, 0.f, 0.f}, a1 = {0.f, 0.f, 0.f, 0.f};
#pragma unroll
          for (int i = 0; i < 8; ++i) {
            short8 af = *(const short8*)(h0r + (mm * 32 + w2 * 8 + i) * 1024 + lane * 16);
            a0 = MFMA(af, wf[i * 2 + 0], a0, 0, 0, 0);
            a1 = MFMA(af, wf[i * 2 + 1], a1, 0, 0, 0);
          }
#pragma unroll
          for (int i = 0; i < 8; ++i) {
            short8 af = *(const short8*)(h1r + (mm * 32 + w2 * 8 + i) * 1024 + lane * 16);
            a0 = MFMA(af, wf[16 + i * 2 + 0], a0, 0, 0, 0);
            a1 = MFMA(af, wf[16 + i * 2 + 1], a1, 0, 0, 0);
          }
          *(f32x4*)(&red[wid][mm][0][lane][0]) = a0;
          *(f32x4*)(&red[wid][mm][1][lane][0]) = a1;
        }
      }
    }
    __syncthreads();   // #1: red[] ready

    // ---------- reduce (K-split over 4 waves) + LSTM epilogue ----------
    if (s < T_STEPS) {
      float sg[4];
#pragma unroll
      for (int g = 0; g < 4; ++g) {
        const int n = g * 8 + j;
        const int nt = n >> 4;
        const int ln = ((r >> 2) << 4) | (n & 15);
        const int rg = r & 3;
        sg[g] = red[0][m][nt][ln][rg] + red[1][m][nt][ln][rg] +
                red[2][m][nt][ln][rg] + red[3][m][nt][ln][rg] + bias0[g];
      }
      const float iv = sigf(sg[0]);
      const float fv = sigf(sg[1]);
      const float gv = tanh_(sg[2]);
      const float ov = sigf(sg[3]);
      c0 = fv * c0 + iv * gv;
      const float h0v = ov * tanh_(c0);
      *(short*)(h0b + p0 * HBUF + hoff) = bf16r(h0v);   // h0(s), cached store
    }
    if (s >= 1) {
      float sg[4];
#pragma unroll
      for (int g = 0; g < 4; ++g) {
        const int n = g * 8 + j;
        const int nt = n >> 4;
        const int ln = ((r >> 2) << 4) | (n & 15);
        const int rg = r & 3;
        sg[g] = red[4][m][nt][ln][rg] + red[5][m][nt][ln][rg] +
                red[6][m][nt][ln][rg] + red[7][m][nt][ln][rg] + bias1[g];
      }
      const float iv = sigf(sg[0]);
      const float fv = sigf(sg[1]);
      const float gv = tanh_(sg[2]);
      const float ov = sigf(sg[3]);
      c1 = fv * c1 + iv * gv;
      const float h1v = ov * tanh_(c1);
      // out is write-once data: non-temporal so it never sits dirty in L2
      // (keeps the release fence's wbl2 cheap — only h lines to flush)
      __builtin_nontemporal_store(sigf(h1v), &out[b * (T_STEPS * HID) + (s - 1) * HID + jg]);
      *(short*)(h1b + (p0 ^ 1) * HBUF + hoff) = bf16r(h1v);   // h1(s-1)
    }

    // all my stores complete (per wave) before block-wide signal
    asm volatile("s_waitcnt vmcnt(0)" ::: "memory");
    __syncthreads();   // #2: red consumed, all waves' stores drained

    if (s < T_STEPS && tid == 0) {
      // release: flush dirty h lines out of this XCD's L2, then signal
      __builtin_amdgcn_fence(__ATOMIC_RELEASE, "agent");
      __hip_atomic_store(&slots[blk], (unsigned)(s + 1),
                         __ATOMIC_RELAXED, __HIP_MEMORY_SCOPE_AGENT);
    }
  }
}

extern "C" void kernel_launch(void* const* d_in, const int* in_sizes, int n_in,
                              void* d_out, int out_size, void* d_ws, size_t ws_size,
                              hipStream_t stream) {
  const float* x    = (const float*)d_in[0];
  const float* Wih0 = (const float*)d_in[1];
  const float* Whh0 = (const float*)d_in[2];
  const float* bih0 = (const float*)d_in[3];
  const float* bhh0 = (const float*)d_in[4];
  const float* Wih1 = (const float*)d_in[5];
  const float* Whh1 = (const float*)d_in[6];
  const float* bih1 = (const float*)d_in[7];
  const float* bhh1 = (const float*)d_in[8];
  unsigned char* ws = (unsigned char*)d_ws;

  // zero barrier slots + h double-buffers (deterministic per call)
  (void)hipMemsetAsync(d_ws, 0, WS_XB, stream);
  hipLaunchKernelGGL(cast_x_kernel, dim3(1024), dim3(256), 0, stream, x, ws);
  hipLaunchKernelGGL(lstm_main, dim3(NBLOCKS), dim3(NTHREADS), 0, stream,
                     Wih0, Whh0, bih0, bhh0, Wih1, Whh1, bih1, bhh1,
                     (float*)d_out, ws);
}

// Round 5
// 6243.348 us; speedup vs baseline: 1.7376x; 1.7376x over previous
//
#include <hip/hip_runtime.h>
#include <hip/hip_bf16.h>

typedef __attribute__((ext_vector_type(8))) short short8;
typedef __attribute__((ext_vector_type(4))) float f32x4;
typedef unsigned long long u64;

#define T_STEPS 512
#define BATCH 64
#define HID 1024
#define DIN 512
#define NBLOCKS 128
#define NTHREADS 512

// ---- workspace layout (bytes) ----
#define WS_GRP 0                // 8 group counters, 128B stride
#define WS_ROOT 2048            // root counter (1 word)
#define WS_H0 4096              // 2 * 131072 (double-buffered h0, bf16 frag tiles)
#define WS_H1 (4096 + 262144)   // 2 * 131072
#define WS_XB (1u << 20)        // x cast to bf16 frag tiles: 32 MB
#define HBUF 131072

#define MFMA __builtin_amdgcn_mfma_f32_16x16x32_bf16

__device__ __forceinline__ short bf16r(float x) {
  unsigned u = __builtin_bit_cast(unsigned, x);
  u += 0x7FFFu + ((u >> 16) & 1u);   // round-to-nearest-even
  return (short)(u >> 16);
}

__device__ __forceinline__ float sigf(float x) {
  return 1.0f / (1.0f + __expf(-x));
}
__device__ __forceinline__ float tanh_(float x) {
  return 2.0f * sigf(2.0f * x) - 1.0f;
}

__device__ __forceinline__ short8 pack8(const float* p) {
  float4 a = *(const float4*)p;
  float4 c = *(const float4*)(p + 4);
  short8 v;
  v[0] = bf16r(a.x); v[1] = bf16r(a.y); v[2] = bf16r(a.z); v[3] = bf16r(a.w);
  v[4] = bf16r(c.x); v[5] = bf16r(c.y); v[6] = bf16r(c.z); v[7] = bf16r(c.w);
  return v;
}

// MALL-coherent 16B fragment load: two 8B agent-scope relaxed atomic loads.
// Bypasses L1/L2 -> always sees peers' released h data, no inv fence needed.
// Compiler tracks these loads (auto vmcnt) so they pipeline normally.
__device__ __forceinline__ short8 ld_frag(const unsigned char* p) {
  union { u64 q[2]; short8 v; } u;
  u.q[0] = __hip_atomic_load((const u64*)p, __ATOMIC_RELAXED, __HIP_MEMORY_SCOPE_AGENT);
  u.q[1] = __hip_atomic_load((const u64*)(p + 8), __ATOMIC_RELAXED, __HIP_MEMORY_SCOPE_AGENT);
  return u.v;
}

// Barrier wait: one lane (tid 256) polls the single root word at agent scope
// with sleep backoff; broadcasts via an LDS generation word. All other waves
// spin on LDS only (zero global traffic, no cache maintenance anywhere).
__device__ __forceinline__ void wait_gen(unsigned* root, unsigned* gen_lds,
                                         unsigned s, int tid) {
  if (tid == 256) {
    const unsigned tgt = 8u * s;   // 8 groups increment root once per interval
    int g = 0;
    while (__hip_atomic_load(root, __ATOMIC_RELAXED, __HIP_MEMORY_SCOPE_AGENT) < tgt) {
      __builtin_amdgcn_s_sleep(2);
      if (++g > (1 << 13)) break;   // anti-hang bail (legit waits are ~µs)
    }
    __hip_atomic_store(gen_lds, s, __ATOMIC_RELEASE, __HIP_MEMORY_SCOPE_WORKGROUP);
  }
  int g = 0;
  while (__hip_atomic_load(gen_lds, __ATOMIC_ACQUIRE, __HIP_MEMORY_SCOPE_WORKGROUP) < s) {
    __builtin_amdgcn_s_sleep(1);
    if (++g > (1 << 15)) break;
  }
}

// Cast x [64][512][512] fp32 -> bf16 MFMA A-fragment tiles:
// xb[t][m=b/16][kt=k/32] tile of 1024B; within tile: lane=(b&15)+16*((k>>3)&3), elem=k&7
__global__ void cast_x_kernel(const float* __restrict__ x, unsigned char* __restrict__ ws) {
  unsigned char* xb = ws + WS_XB;
  int idx = blockIdx.x * blockDim.x + threadIdx.x;   // 0..262143
  for (int c = idx; c < 64 * 512 * 64; c += 262144) {
    const int b = c >> 15;
    const int t = (c >> 6) & 511;
    const int kc = c & 63;
    const float* src = x + (((b << 9) + t) << 9) + (kc << 3);
    short8 v = pack8(src);
    const int kt = kc >> 2;
    const int ln = (b & 15) + ((kc & 3) << 4);
    unsigned char* dst = xb + (((t << 2) + (b >> 4)) * 16 + kt) * 1024 + ln * 16;
    *(short8*)dst = v;
  }
}

__global__ __launch_bounds__(NTHREADS, 2) void lstm_main(
    const float* __restrict__ Wih0, const float* __restrict__ Whh0,
    const float* __restrict__ bih0, const float* __restrict__ bhh0,
    const float* __restrict__ Wih1, const float* __restrict__ Whh1,
    const float* __restrict__ bih1, const float* __restrict__ bhh1,
    float* __restrict__ out, unsigned char* __restrict__ ws)
{
  __shared__ float red[8][4][2][64][4];   // [wave][Mtile][Ntile][lane][reg] = 64 KB
  __shared__ unsigned gen_lds;

  const int tid = threadIdx.x;
  const int wid = tid >> 6;
  const int lane = tid & 63;
  const int blk = blockIdx.x;

  unsigned* grp = (unsigned*)(ws + WS_GRP);
  unsigned* root = (unsigned*)(ws + WS_ROOT);
  unsigned char* h0b = ws + WS_H0;
  unsigned char* h1b = ws + WS_H1;
  const unsigned char* xb = ws + WS_XB;

  // ---------- persistent weight fragments (128 VGPRs) ----------
  // Block owns gate columns col = blk*8 + (0..7) for BOTH layers.
  // Ntile n in 0..31: gate = n>>3 (i,f,g,o), col = blk*8 + (n&7); weight row = gate*1024+col.
  // B-fragment slot (lane, e): n = lane&15 (+16*nt), k = kbase + 8*(lane>>4) + e.
  short8 wf[32];
  {
    const int hi8 = (lane >> 4) << 3;
    if (wid < 4) {
      // A-waves: layer0. x-ktiles wid*4+i (i<4), h0-ktiles wid*8+i (i<8)
#pragma unroll
      for (int nt = 0; nt < 2; ++nt) {
        const int n = nt * 16 + (lane & 15);
        const int row = ((n >> 3) << 10) + blk * 8 + (n & 7);
#pragma unroll
        for (int i = 0; i < 4; ++i) {
          const int k = (wid * 4 + i) * 32 + hi8;
          wf[i * 2 + nt] = pack8(Wih0 + row * DIN + k);
        }
#pragma unroll
        for (int i = 0; i < 8; ++i) {
          const int k = (wid * 8 + i) * 32 + hi8;
          wf[8 + i * 2 + nt] = pack8(Whh0 + row * HID + k);
        }
      }
    } else {
      // B-waves: layer1. h0-ktiles w2*8+i and h1-ktiles w2*8+i
      const int w2 = wid - 4;
#pragma unroll
      for (int nt = 0; nt < 2; ++nt) {
        const int n = nt * 16 + (lane & 15);
        const int row = ((n >> 3) << 10) + blk * 8 + (n & 7);
#pragma unroll
        for (int i = 0; i < 8; ++i) {
          const int k = (w2 * 8 + i) * 32 + hi8;
          wf[i * 2 + nt] = pack8(Wih1 + row * HID + k);
          wf[16 + i * 2 + nt] = pack8(Whh1 + row * HID + k);
        }
      }
    }
  }

  // ---------- per-thread epilogue state ----------
  const int j = tid & 7;
  const int b = tid >> 3;          // batch row 0..63
  const int jg = blk * 8 + j;      // global h column
  const int m = b >> 4;            // Mtile
  const int r = b & 15;            // row within tile
  float bias0[4], bias1[4];
#pragma unroll
  for (int g = 0; g < 4; ++g) {
    bias0[g] = bih0[g * HID + jg] + bhh0[g * HID + jg];
    bias1[g] = bih1[g * HID + jg] + bhh1[g * HID + jg];
  }
  float c0 = 0.0f, c1 = 0.0f;
  // byte offset of h(b, jg) inside one parity buffer (frag tile layout);
  // for even j this is 4B-aligned (consecutive j are consecutive 2B)
  const int hoff = ((b >> 4) * 32 + (jg >> 5)) * 1024 +
                   ((b & 15) + 16 * ((jg >> 3) & 3)) * 16 + (jg & 7) * 2;

  if (tid == 0) __hip_atomic_store(&gen_lds, 0u, __ATOMIC_RELAXED, __HIP_MEMORY_SCOPE_WORKGROUP);
  __syncthreads();

  // ---------- wavefront loop: interval s computes layer0(s) and layer1(s-1) ----------
  for (int s = 0; s <= T_STEPS; ++s) {
    const int p0 = s & 1;
    const unsigned char* h0r = h0b + (p0 ^ 1) * HBUF;   // h0(s-1)

    // A-waves: x part first — no barrier dependency, overlaps the wait
    f32x4 acc[4][2];
    if (wid < 4 && s < T_STEPS) {
      const unsigned char* xs = xb + s * 65536;
#pragma unroll
      for (int mm = 0; mm < 4; ++mm) {
        acc[mm][0] = (f32x4){0.f, 0.f, 0.f, 0.f};
        acc[mm][1] = (f32x4){0.f, 0.f, 0.f, 0.f};
#pragma unroll
        for (int i = 0; i < 4; ++i) {
          short8 af = *(const short8*)(xs + (mm * 16 + wid * 4 + i) * 1024 + lane * 16);
          acc[mm][0] = MFMA(af, wf[i * 2 + 0], acc[mm][0], 0, 0, 0);
          acc[mm][1] = MFMA(af, wf[i * 2 + 1], acc[mm][1], 0, 0, 0);
        }
      }
    }

    wait_gen(root, &gen_lds, (unsigned)s, tid);   // h0(s-1)/h1(s-2) at MALL

    if (wid < 4) {
      if (s < T_STEPS) {
#pragma unroll
        for (int mm = 0; mm < 4; ++mm) {
#pragma unroll
          for (int i = 0; i < 8; ++i) {
            short8 af = ld_frag(h0r + (mm * 32 + wid * 8 + i) * 1024 + lane * 16);
            acc[mm][0] = MFMA(af, wf[8 + i * 2 + 0], acc[mm][0], 0, 0, 0);
            acc[mm][1] = MFMA(af, wf[8 + i * 2 + 1], acc[mm][1], 0, 0, 0);
          }
          *(f32x4*)(&red[wid][mm][0][lane][0]) = acc[mm][0];
          *(f32x4*)(&red[wid][mm][1][lane][0]) = acc[mm][1];
        }
      }
    } else {
      if (s >= 1) {
        const unsigned char* h1r = h1b + p0 * HBUF;     // h1(s-2)
        const int w2 = wid - 4;
        for (int mm = 0; mm < 4; ++mm) {
          f32x4 a0 = {0.f, 0.f, 0.f, 0.f}, a1 = {0.f, 0.f, 0.f, 0.f};
#pragma unroll
          for (int i = 0; i < 8; ++i) {
            short8 af = ld_frag(h0r + (mm * 32 + w2 * 8 + i) * 1024 + lane * 16);
            a0 = MFMA(af, wf[i * 2 + 0], a0, 0, 0, 0);
            a1 = MFMA(af, wf[i * 2 + 1], a1, 0, 0, 0);
          }
#pragma unroll
          for (int i = 0; i < 8; ++i) {
            short8 af = ld_frag(h1r + (mm * 32 + w2 * 8 + i) * 1024 + lane * 16);
            a0 = MFMA(af, wf[16 + i * 2 + 0], a0, 0, 0, 0);
            a1 = MFMA(af, wf[16 + i * 2 + 1], a1, 0, 0, 0);
          }
          *(f32x4*)(&red[wid][mm][0][lane][0]) = a0;
          *(f32x4*)(&red[wid][mm][1][lane][0]) = a1;
        }
      }
    }
    __syncthreads();   // #1: red[] ready

    // ---------- reduce (K-split over 4 waves) + LSTM epilogue ----------
    if (s < T_STEPS) {
      float sg[4];
#pragma unroll
      for (int g = 0; g < 4; ++g) {
        const int n = g * 8 + j;
        const int nt = n >> 4;
        const int ln = ((r >> 2) << 4) | (n & 15);
        const int rg = r & 3;
        sg[g] = red[0][m][nt][ln][rg] + red[1][m][nt][ln][rg] +
                red[2][m][nt][ln][rg] + red[3][m][nt][ln][rg] + bias0[g];
      }
      const float iv = sigf(sg[0]);
      const float fv = sigf(sg[1]);
      const float gv = tanh_(sg[2]);
      const float ov = sigf(sg[3]);
      c0 = fv * c0 + iv * gv;
      const float h0v = ov * tanh_(c0);
      // pack 2 adjacent columns' bf16 into one 4B agent-atomic store (MALL-visible)
      unsigned hb = (unsigned)bf16r(h0v) & 0xFFFFu;
      unsigned nb = (unsigned)__shfl_down((int)hb, 1) & 0xFFFFu;
      if ((j & 1) == 0)
        __hip_atomic_store((unsigned*)(h0b + p0 * HBUF + hoff), hb | (nb << 16),
                           __ATOMIC_RELAXED, __HIP_MEMORY_SCOPE_AGENT);
    }
    if (s >= 1) {
      float sg[4];
#pragma unroll
      for (int g = 0; g < 4; ++g) {
        const int n = g * 8 + j;
        const int nt = n >> 4;
        const int ln = ((r >> 2) << 4) | (n & 15);
        const int rg = r & 3;
        sg[g] = red[4][m][nt][ln][rg] + red[5][m][nt][ln][rg] +
                red[6][m][nt][ln][rg] + red[7][m][nt][ln][rg] + bias1[g];
      }
      const float iv = sigf(sg[0]);
      const float fv = sigf(sg[1]);
      const float gv = tanh_(sg[2]);
      const float ov = sigf(sg[3]);
      c1 = fv * c1 + iv * gv;
      const float h1v = ov * tanh_(c1);
      // out is write-once: non-temporal keeps L2 clean for x tiles
      __builtin_nontemporal_store(sigf(h1v), &out[b * (T_STEPS * HID) + (s - 1) * HID + jg]);
      unsigned hb = (unsigned)bf16r(h1v) & 0xFFFFu;
      unsigned nb = (unsigned)__shfl_down((int)hb, 1) & 0xFFFFu;
      if ((j & 1) == 0)
        __hip_atomic_store((unsigned*)(h1b + (p0 ^ 1) * HBUF + hoff), hb | (nb << 16),
                           __ATOMIC_RELAXED, __HIP_MEMORY_SCOPE_AGENT);
    }

    // my stores acked at coherence point before block-wide signal
    asm volatile("s_waitcnt vmcnt(0)" ::: "memory");
    __syncthreads();   // #2: red consumed, all waves' stores drained

    if (s < T_STEPS && tid == 0) {
      // no fence needed: h went to MALL via atomics; just count arrivals
      unsigned v = __hip_atomic_fetch_add(&grp[(blk >> 4) * 32], 1u,
                                          __ATOMIC_RELAXED, __HIP_MEMORY_SCOPE_AGENT);
      if ((v & 15) == 15)
        __hip_atomic_fetch_add(root, 1u, __ATOMIC_RELAXED, __HIP_MEMORY_SCOPE_AGENT);
    }
  }
}

extern "C" void kernel_launch(void* const* d_in, const int* in_sizes, int n_in,
                              void* d_out, int out_size, void* d_ws, size_t ws_size,
                              hipStream_t stream) {
  const float* x    = (const float*)d_in[0];
  const float* Wih0 = (const float*)d_in[1];
  const float* Whh0 = (const float*)d_in[2];
  const float* bih0 = (const float*)d_in[3];
  const float* bhh0 = (const float*)d_in[4];
  const float* Wih1 = (const float*)d_in[5];
  const float* Whh1 = (const float*)d_in[6];
  const float* bih1 = (const float*)d_in[7];
  const float* bhh1 = (const float*)d_in[8];
  unsigned char* ws = (unsigned char*)d_ws;

  // zero barrier counters + h double-buffers (deterministic per call)
  (void)hipMemsetAsync(d_ws, 0, WS_XB, stream);
  hipLaunchKernelGGL(cast_x_kernel, dim3(1024), dim3(256), 0, stream, x, ws);
  hipLaunchKernelGGL(lstm_main, dim3(NBLOCKS), dim3(NTHREADS), 0, stream,
                     Wih0, Whh0, bih0, bhh0, Wih1, Whh1, bih1, bhh1,
                     (float*)d_out, ws);
}